// Round 9
// baseline (166.241 us; speedup 1.0000x reference)
//
#include <hip/hip_runtime.h>
#include <hip/hip_bf16.h>

#define B_  2
#define S_  2048
#define D_  1024
#define H_  16
#define DK_ 64
#define M_  (B_ * S_)   // 4096

typedef short short8 __attribute__((ext_vector_type(8)));
typedef float float4v __attribute__((ext_vector_type(4)));

// log2(e)/8 : folded into Q at projection so attention exp is a bare v_exp_f32
#define QSCALE 0.18033688011112042f

static __device__ __forceinline__ ushort f32_to_bf16bits(float f) {
    union { __hip_bfloat16 h; ushort u; } cv;
    cv.h = __float2bfloat16(f);
    return cv.u;
}

// async global->LDS, 16B per lane (lands at wave-uniform base + lane*16)
static __device__ __forceinline__ void glds16(const ushort* g, ushort* l) {
    __builtin_amdgcn_global_load_lds(
        (const __attribute__((address_space(1))) unsigned int*)g,
        (__attribute__((address_space(3))) unsigned int*)l, 16, 0, 0);
}

// ---------------------------------------------------------------------------
// prep: z in [0,3) -> transpose+convert W_z[k][n] fp32 -> Wt[n][k] bf16
//       z in [3,11) -> convert X fp32 -> bf16
// ---------------------------------------------------------------------------
__global__ __launch_bounds__(256) void prep(
    const float* __restrict__ X, const float* __restrict__ W0,
    const float* __restrict__ W1, const float* __restrict__ W2,
    ushort* __restrict__ Xb, ushort* __restrict__ Wt)
{
    const int z = blockIdx.z;
    const int t = threadIdx.x;

    if (z >= 3) {   // convert X
        const int blk = (z - 3) * 256 + blockIdx.y * 16 + blockIdx.x;
        const int i = blk * 2048 + t * 8;
        float4v a = *(const float4v*)(X + i);
        float4v b = *(const float4v*)(X + i + 4);
        short8 o;
        o[0] = (short)f32_to_bf16bits(a[0]); o[1] = (short)f32_to_bf16bits(a[1]);
        o[2] = (short)f32_to_bf16bits(a[2]); o[3] = (short)f32_to_bf16bits(a[3]);
        o[4] = (short)f32_to_bf16bits(b[0]); o[5] = (short)f32_to_bf16bits(b[1]);
        o[6] = (short)f32_to_bf16bits(b[2]); o[7] = (short)f32_to_bf16bits(b[3]);
        *(short8*)(Xb + i) = o;
        return;
    }

    const float* W = (z == 0) ? W0 : ((z == 1) ? W1 : W2);
    ushort* out = Wt + (size_t)z * D_ * D_;

    __shared__ ushort tile[64 * 72];
    int n0 = blockIdx.x * 64, k0 = blockIdx.y * 64;
    int r = t >> 3, g = t & 7;

    #pragma unroll
    for (int p = 0; p < 2; ++p) {
        int rr = r + p * 32;
        const float* src = W + (size_t)(k0 + rr) * D_ + n0 + g * 8;
        float4v a = *(const float4v*)src;
        float4v b = *(const float4v*)(src + 4);
        short8 o;
        o[0] = (short)f32_to_bf16bits(a[0]); o[1] = (short)f32_to_bf16bits(a[1]);
        o[2] = (short)f32_to_bf16bits(a[2]); o[3] = (short)f32_to_bf16bits(a[3]);
        o[4] = (short)f32_to_bf16bits(b[0]); o[5] = (short)f32_to_bf16bits(b[1]);
        o[6] = (short)f32_to_bf16bits(b[2]); o[7] = (short)f32_to_bf16bits(b[3]);
        *(short8*)&tile[rr * 72 + g * 8] = o;
    }
    __syncthreads();
    #pragma unroll
    for (int p = 0; p < 2; ++p) {
        int rr = r + p * 32;
        short8 v;
        #pragma unroll
        for (int i = 0; i < 8; ++i)
            v[i] = (short)tile[(g * 8 + i) * 72 + rr];
        *(short8*)(out + (size_t)(n0 + rr) * D_ + k0 + g * 8) = v;
    }
}

// ---------------------------------------------------------------------------
// FUSED-z QKV projection, 64x64 tile: one block computes q,k,v for an
// (m 64, n 64) tile.  A staged once per iter, 3 B panels; 32 KB LDS ->
// 4 blocks/CU (was 2 at 56 KB) -- the kernel is ~85% latency-idle, so
// resident-block overlap is the binding resource, not per-barrier MFMA.
// Flat grid, m fastest: interleaves kv-skip holes.
// z==0 (Q) epilogue folds score-scale*log2(e) into the values.
// ---------------------------------------------------------------------------
__global__ __launch_bounds__(256, 4) void proj_gemm(
    const ushort* __restrict__ X,    // [4096][1024] bf16
    const ushort* __restrict__ Wt,   // [3][1024][1024] bf16, n-major
    const float* __restrict__ b0, const float* __restrict__ b1,
    const float* __restrict__ b2,
    const int* __restrict__ length,
    ushort* __restrict__ qkv)        // [3][4M] bf16
{
    const int bx = blockIdx.x;
    const int m0 = (bx & 63) * 64;        // m fastest
    const int n0 = (bx >> 6) * 64;
    const int bidx = m0 >> 11;
    const int s0 = m0 & (S_ - 1);
    const bool kv = (s0 < length[bidx]);  // block-uniform

    __shared__ __align__(16) ushort As[64 * 64];       //  8 KB
    __shared__ __align__(16) ushort Bs[3][64 * 64];    // 24 KB

    const int t = threadIdx.x;
    const int lane = t & 63, wid = t >> 6;
    const int quad = lane >> 4, l16 = lane & 15;
    const int wr = wid >> 1, wc = wid & 1;

    float4v accq[2][2] = {}, acck[2][2] = {}, accv[2][2] = {};

    for (int kt = 0; kt < 16; ++kt) {
        const int k0 = kt * 64;
        __syncthreads();
        #pragma unroll
        for (int j = 0; j < 2; ++j) {      // 512 chunks per panel, 128/wave
            const int cid = wid * 128 + j * 64 + lane;
            const int row = cid >> 3;
            const int cl  = (cid & 7) ^ (row & 7);
            glds16(X + (size_t)(m0 + row) * D_ + k0 + cl * 8, &As[cid * 8]);
            const size_t off = (size_t)(n0 + row) * D_ + k0 + cl * 8;
            glds16(Wt + off, &Bs[0][cid * 8]);
            if (kv) {
                glds16(Wt + (size_t)D_ * D_ + off,     &Bs[1][cid * 8]);
                glds16(Wt + (size_t)2 * D_ * D_ + off, &Bs[2][cid * 8]);
            }
        }
        __syncthreads();

        #pragma unroll
        for (int ks = 0; ks < 2; ++ks) {
            short8 a[2];
            #pragma unroll
            for (int i = 0; i < 2; ++i) {
                const int r = wr * 32 + i * 16 + l16;
                const int ph = (ks * 4 + quad) ^ (r & 7);
                a[i] = *(short8*)&As[r * 64 + ph * 8];
            }
            short8 bq[2];
            #pragma unroll
            for (int j = 0; j < 2; ++j) {
                const int r = wc * 32 + j * 16 + l16;
                const int ph = (ks * 4 + quad) ^ (r & 7);
                bq[j] = *(short8*)&Bs[0][r * 64 + ph * 8];
            }
            #pragma unroll
            for (int i = 0; i < 2; ++i)
                #pragma unroll
                for (int j = 0; j < 2; ++j)
                    accq[i][j] = __builtin_amdgcn_mfma_f32_16x16x32_bf16(
                        a[i], bq[j], accq[i][j], 0, 0, 0);
            if (kv) {
                short8 bk[2], bv[2];
                #pragma unroll
                for (int j = 0; j < 2; ++j) {
                    const int r = wc * 32 + j * 16 + l16;
                    const int ph = (ks * 4 + quad) ^ (r & 7);
                    bk[j] = *(short8*)&Bs[1][r * 64 + ph * 8];
                    bv[j] = *(short8*)&Bs[2][r * 64 + ph * 8];
                }
                #pragma unroll
                for (int i = 0; i < 2; ++i)
                    #pragma unroll
                    for (int j = 0; j < 2; ++j) {
                        acck[i][j] = __builtin_amdgcn_mfma_f32_16x16x32_bf16(
                            a[i], bk[j], acck[i][j], 0, 0, 0);
                        accv[i][j] = __builtin_amdgcn_mfma_f32_16x16x32_bf16(
                            a[i], bv[j], accv[i][j], 0, 0, 0);
                    }
            }
        }
    }

    // epilogue: +bias, scatter into head layouts.
    #pragma unroll
    for (int j = 0; j < 2; ++j) {
        const int col = n0 + wc * 32 + j * 16 + l16;
        const int h = col >> 6, dk = col & (DK_ - 1);
        const float bvq = b0[col], bvk = b1[col], bvv = b2[col];
        #pragma unroll
        for (int i = 0; i < 2; ++i) {
            #pragma unroll
            for (int rr = 0; rr < 4; ++rr) {
                const int row = m0 + wr * 32 + i * 16 + quad * 4 + rr;
                const int s = row & (S_ - 1);
                const size_t hdr = ((size_t)(bidx * H_ + h) * S_ + s) * DK_ + dk;
                qkv[hdr] = f32_to_bf16bits((accq[i][j][rr] + bvq) * QSCALE);
                if (kv) {
                    qkv[(size_t)M_ * D_ + hdr] =
                        f32_to_bf16bits(acck[i][j][rr] + bvk);
                    qkv[(size_t)2 * M_ * D_ +
                        ((size_t)(bidx * H_ + h) * DK_ + dk) * S_ + s] =
                        f32_to_bf16bits(accv[i][j][rr] + bvv);
                }
            }
        }
    }
}

// ---------------------------------------------------------------------------
// attention: block = (b, h, 64 q-rows), 4 waves x 16-q strips.
// S^T trick (S^T = K*Q^T) -> packed P writes.  Q frags hoisted; Qs LDS is
// then DEAD and reused as Ps (both touch only wave-private rows 16w..16w+16,
// so no barrier needed) -> 40 KB LDS = 4 blocks/CU.
// Row-sums via ones-MFMA (C-layout lands rowsum in the normalizing lane).
// P packed by truncation (bias cancels in P/sum(P)).  Flat grid, (b,h)
// fastest: interleaves short/long-length blocks.
// ---------------------------------------------------------------------------
__global__ __launch_bounds__(256, 4) void attention(
    const ushort* __restrict__ qkv, const int* __restrict__ length,
    float* __restrict__ out)
{
    const int bx = blockIdx.x;
    const int b = bx & 1, h = (bx >> 1) & 15, q0 = (bx >> 5) * 64;
    int len = length[b];
    if (len > S_) len = S_;
    if (len < 1) len = 1;
    const int nkt = (len + 63) >> 6;

    const ushort* qb = qkv + ((size_t)(b * H_ + h) * S_ + q0) * DK_;
    const ushort* kb = qkv + (size_t)M_ * D_ + (size_t)(b * H_ + h) * S_ * DK_;
    const ushort* vb = qkv + (size_t)2 * M_ * D_ + (size_t)(b * H_ + h) * DK_ * S_;

    __shared__ __align__(16) ushort QPs[64 * 64];      //  8 KB Q then P (union)
    __shared__ __align__(16) ushort Ks[2][64 * 64];    // 16 KB [key][dk]
    __shared__ __align__(16) ushort Vs[2][64 * 64];    // 16 KB [dk][key]

    const int t = threadIdx.x, lane = t & 63, wid = t >> 6;
    const int quad = lane >> 4, l16 = lane & 15;
    const int qrow = wid * 16 + l16;
    const int e8 = (l16 & 7) << 1;   // even XOR phase for Ps (row&7 == l16&7)

    // stage Q (once) + K/V tile 0
    #pragma unroll
    for (int j = 0; j < 2; ++j) {
        const int cid = wid * 128 + j * 64 + lane;
        const int row = cid >> 3;
        const int cl  = (cid & 7) ^ (row & 7);
        glds16(qb + (size_t)row * DK_ + cl * 8, &QPs[cid * 8]);
        glds16(kb + (size_t)row * DK_ + cl * 8, &Ks[0][cid * 8]);
        glds16(vb + (size_t)row * S_ + cl * 8,  &Vs[0][cid * 8]);
    }
    __syncthreads();

    // hoist Q fragments (loop-invariant); QPs rows [16w,16w+16) then free
    short8 qfrag[2];
    #pragma unroll
    for (int ks = 0; ks < 2; ++ks) {
        const int phb = (ks * 4 + quad) ^ (l16 & 7);
        qfrag[ks] = *(short8*)&QPs[qrow * 64 + phb * 8];
    }

    // bf16 ones fragment for the rowsum MFMA
    short8 ones8;
    #pragma unroll
    for (int i = 0; i < 8; ++i) ones8[i] = (short)0x3F80;

    float4v cacc[4] = {};
    float4v racc = {};

    for (int kt = 0; kt < nkt; ++kt) {
        const int cur = kt & 1, nxt = cur ^ 1;
        if (kt + 1 < nkt) {
            #pragma unroll
            for (int j = 0; j < 2; ++j) {
                const int cid = wid * 128 + j * 64 + lane;
                const int row = cid >> 3;
                const int cl  = (cid & 7) ^ (row & 7);
                glds16(kb + (size_t)((kt + 1) * 64 + row) * DK_ + cl * 8,
                       &Ks[nxt][cid * 8]);
                glds16(vb + (size_t)row * S_ + (kt + 1) * 64 + cl * 8,
                       &Vs[nxt][cid * 8]);
            }
        }

        // S^T tile: A = K-frag (m=key), B = Q-frag (n=q).  D[key][q]:
        // lane holds q = l16 (col), keys = ct*16 + quad*4 + rr (rows).
        float4v sacc[4] = {};
        #pragma unroll
        for (int ks = 0; ks < 2; ++ks) {
            #pragma unroll
            for (int ct = 0; ct < 4; ++ct) {
                const int krow = ct * 16 + l16;
                const int pha = (ks * 4 + quad) ^ (krow & 7);
                short8 ak = *(short8*)&Ks[cur][krow * 64 + pha * 8];
                sacc[ct] = __builtin_amdgcn_mfma_f32_16x16x32_bf16(
                    ak, qfrag[ks], sacc[ct], 0, 0, 0);
            }
        }

        // exp2 + (boundary-only) mask + truncation-packed P write
        const bool full = ((kt + 1) * 64 <= len);
        #pragma unroll
        for (int ct = 0; ct < 4; ++ct) {
            float v0 = __builtin_amdgcn_exp2f(sacc[ct][0]);
            float v1 = __builtin_amdgcn_exp2f(sacc[ct][1]);
            float v2 = __builtin_amdgcn_exp2f(sacc[ct][2]);
            float v3 = __builtin_amdgcn_exp2f(sacc[ct][3]);
            if (!full) {
                const int kb0 = kt * 64 + ct * 16 + quad * 4;
                v0 = (kb0 + 0 < len) ? v0 : 0.f;
                v1 = (kb0 + 1 < len) ? v1 : 0.f;
                v2 = (kb0 + 2 < len) ? v2 : 0.f;
                v3 = (kb0 + 3 < len) ? v3 : 0.f;
            }
            uint2 w;
            w.x = (__float_as_uint(v0) >> 16) | (__float_as_uint(v1) & 0xFFFF0000u);
            w.y = (__float_as_uint(v2) >> 16) | (__float_as_uint(v3) & 0xFFFF0000u);
            const int c8 = (ct * 4 + quad) ^ e8;        // 8B-chunk swizzle
            *(uint2*)&QPs[qrow * 64 + c8 * 4] = w;
        }

        // P @ V  (+ rowsum via ones-MFMA, reusing the A-fragment).
        // Strip is wave-private: same-wave LDS RAW, no barrier needed.
        #pragma unroll
        for (int ks = 0; ks < 2; ++ks) {
            const int pp = ((ks * 4 + quad) * 2) ^ e8;   // first 8B chunk (even)
            short8 ap = *(short8*)&QPs[qrow * 64 + pp * 4];
            #pragma unroll
            for (int ct = 0; ct < 4; ++ct) {
                const int vrow = ct * 16 + l16;
                const int phv = (ks * 4 + quad) ^ (vrow & 7);
                short8 vv = *(short8*)&Vs[cur][vrow * 64 + phv * 8];
                cacc[ct] = __builtin_amdgcn_mfma_f32_16x16x32_bf16(
                    ap, vv, cacc[ct], 0, 0, 0);
            }
            racc = __builtin_amdgcn_mfma_f32_16x16x32_bf16(
                ap, ones8, racc, 0, 0, 0);
        }
        __syncthreads();   // next-stage glds drained; buf[cur] free for kt+2
    }

    // normalize + store fp32.  racc[rr] holds rowsum for q = quad*4+rr in
    // every l16 lane -- exactly where cacc[ct][rr] needs it.  No shuffles.
    #pragma unroll
    for (int rr = 0; rr < 4; ++rr) {
        const float inv = 1.0f / (racc[rr] + 1e-8f);
        const int q = q0 + wid * 16 + quad * 4 + rr;
        #pragma unroll
        for (int ct = 0; ct < 4; ++ct) {
            const int d = h * 64 + ct * 16 + l16;
            out[((size_t)b * S_ + q) * D_ + d] = cacc[ct][rr] * inv;
        }
    }
}

// ---------------------------------------------------------------------------
extern "C" void kernel_launch(void* const* d_in, const int* in_sizes, int n_in,
                              void* d_out, int out_size, void* d_ws, size_t ws_size,
                              hipStream_t stream)
{
    const float* Q   = (const float*)d_in[0];
    const int*   len = (const int*)d_in[1];
    const float* Wq  = (const float*)d_in[2];
    const float* bq  = (const float*)d_in[3];
    const float* Wk  = (const float*)d_in[4];
    const float* bk  = (const float*)d_in[5];
    const float* Wv  = (const float*)d_in[6];
    const float* bv  = (const float*)d_in[7];
    float* out = (float*)d_out;

    ushort* ws  = (ushort*)d_ws;
    ushort* Xb  = ws;                                   // 4M bf16 = 8 MB
    ushort* Wt  = ws + (size_t)M_ * D_;                 // 3M bf16 = 6 MB
    ushort* qkv = Wt + (size_t)3 * D_ * D_;             // 12M bf16 = 24 MB

    dim3 gPr(16, 16, 11);
    prep<<<gPr, 256, 0, stream>>>(Q, Wq, Wk, Wv, Xb, Wt);

    // flat grid, m fastest: 64 m-tiles x 16 n-tiles
    proj_gemm<<<dim3(64 * 16), 256, 0, stream>>>(Xb, Wt, bq, bk, bv, len, qkv);

    // flat grid, (b,h) fastest: 2 x 16 x 32 q-tiles
    attention<<<dim3(2 * 16 * 32), 256, 0, stream>>>(qkv, len, out);
}

// Round 10
// 162.402 us; speedup vs baseline: 1.0236x; 1.0236x over previous
//
#include <hip/hip_runtime.h>
#include <hip/hip_bf16.h>

#define B_  2
#define S_  2048
#define D_  1024
#define H_  16
#define DK_ 64
#define M_  (B_ * S_)   // 4096

typedef short short8 __attribute__((ext_vector_type(8)));
typedef float float4v __attribute__((ext_vector_type(4)));
typedef float float16v __attribute__((ext_vector_type(16)));

// log2(e)/8 : folded into Q at projection so attention exp is a bare v_exp_f32
#define QSCALE 0.18033688011112042f

static __device__ __forceinline__ ushort f32_to_bf16bits(float f) {
    union { __hip_bfloat16 h; ushort u; } cv;
    cv.h = __float2bfloat16(f);
    return cv.u;
}

// async global->LDS, 16B per lane (lands at wave-uniform base + lane*16)
static __device__ __forceinline__ void glds16(const ushort* g, ushort* l) {
    __builtin_amdgcn_global_load_lds(
        (const __attribute__((address_space(1))) unsigned int*)g,
        (__attribute__((address_space(3))) unsigned int*)l, 16, 0, 0);
}

// ---------------------------------------------------------------------------
// prep: z in [0,3) -> transpose+convert W_z[k][n] fp32 -> Wt[n][k] bf16
//       z in [3,11) -> convert X fp32 -> bf16
// ---------------------------------------------------------------------------
__global__ __launch_bounds__(256) void prep(
    const float* __restrict__ X, const float* __restrict__ W0,
    const float* __restrict__ W1, const float* __restrict__ W2,
    ushort* __restrict__ Xb, ushort* __restrict__ Wt)
{
    const int z = blockIdx.z;
    const int t = threadIdx.x;

    if (z >= 3) {   // convert X
        const int blk = (z - 3) * 256 + blockIdx.y * 16 + blockIdx.x;
        const int i = blk * 2048 + t * 8;
        float4v a = *(const float4v*)(X + i);
        float4v b = *(const float4v*)(X + i + 4);
        short8 o;
        o[0] = (short)f32_to_bf16bits(a[0]); o[1] = (short)f32_to_bf16bits(a[1]);
        o[2] = (short)f32_to_bf16bits(a[2]); o[3] = (short)f32_to_bf16bits(a[3]);
        o[4] = (short)f32_to_bf16bits(b[0]); o[5] = (short)f32_to_bf16bits(b[1]);
        o[6] = (short)f32_to_bf16bits(b[2]); o[7] = (short)f32_to_bf16bits(b[3]);
        *(short8*)(Xb + i) = o;
        return;
    }

    const float* W = (z == 0) ? W0 : ((z == 1) ? W1 : W2);
    ushort* out = Wt + (size_t)z * D_ * D_;

    __shared__ ushort tile[64 * 72];
    int n0 = blockIdx.x * 64, k0 = blockIdx.y * 64;
    int r = t >> 3, g = t & 7;

    #pragma unroll
    for (int p = 0; p < 2; ++p) {
        int rr = r + p * 32;
        const float* src = W + (size_t)(k0 + rr) * D_ + n0 + g * 8;
        float4v a = *(const float4v*)src;
        float4v b = *(const float4v*)(src + 4);
        short8 o;
        o[0] = (short)f32_to_bf16bits(a[0]); o[1] = (short)f32_to_bf16bits(a[1]);
        o[2] = (short)f32_to_bf16bits(a[2]); o[3] = (short)f32_to_bf16bits(a[3]);
        o[4] = (short)f32_to_bf16bits(b[0]); o[5] = (short)f32_to_bf16bits(b[1]);
        o[6] = (short)f32_to_bf16bits(b[2]); o[7] = (short)f32_to_bf16bits(b[3]);
        *(short8*)&tile[rr * 72 + g * 8] = o;
    }
    __syncthreads();
    #pragma unroll
    for (int p = 0; p < 2; ++p) {
        int rr = r + p * 32;
        short8 v;
        #pragma unroll
        for (int i = 0; i < 8; ++i)
            v[i] = (short)tile[(g * 8 + i) * 72 + rr];
        *(short8*)(out + (size_t)(n0 + rr) * D_ + k0 + g * 8) = v;
    }
}

// ---------------------------------------------------------------------------
// FUSED-z QKV projection (round-7 best-known): one block = (m 64, n 128)
// computing q, k AND v.  A staged once, 48 MFMA per barrier pair; 56 KB LDS
// = 2 blocks/CU.  k/v skipped (block-uniform) beyond length[b].
// z==0 (Q) epilogue folds score-scale*log2(e) into the values.
// ---------------------------------------------------------------------------
__global__ __launch_bounds__(256, 2) void proj_gemm(
    const ushort* __restrict__ X,    // [4096][1024] bf16
    const ushort* __restrict__ Wt,   // [3][1024][1024] bf16, n-major
    const float* __restrict__ b0, const float* __restrict__ b1,
    const float* __restrict__ b2,
    const int* __restrict__ length,
    ushort* __restrict__ qkv)        // [3][4M] bf16
{
    const int m0 = blockIdx.x * 64, n0 = blockIdx.y * 128;
    const int bidx = m0 >> 11;
    const int s0 = m0 & (S_ - 1);
    const bool kv = (s0 < length[bidx]);   // block-uniform

    __shared__ __align__(16) ushort As[64 * 64];        //  8 KB
    __shared__ __align__(16) ushort Bs[3][128 * 64];    // 48 KB

    const int t = threadIdx.x;
    const int lane = t & 63, wid = t >> 6;
    const int quad = lane >> 4, l16 = lane & 15;
    const int wr = wid >> 1, wc = wid & 1;

    float4v accq[2][4] = {}, acck[2][4] = {}, accv[2][4] = {};

    for (int kt = 0; kt < 16; ++kt) {
        const int k0 = kt * 64;
        __syncthreads();
        #pragma unroll
        for (int j = 0; j < 2; ++j) {          // A: 512 chunks, 128/wave
            const int cid = wid * 128 + j * 64 + lane;
            const int row = cid >> 3;
            const int cl  = (cid & 7) ^ (row & 7);
            glds16(X + (size_t)(m0 + row) * D_ + k0 + cl * 8, &As[cid * 8]);
        }
        #pragma unroll
        for (int j = 0; j < 4; ++j) {          // B panels: 1024 chunks each
            const int cid = wid * 256 + j * 64 + lane;
            const int row = cid >> 3;
            const int cl  = (cid & 7) ^ (row & 7);
            const size_t off = (size_t)(n0 + row) * D_ + k0 + cl * 8;
            glds16(Wt + off, &Bs[0][cid * 8]);
            if (kv) {
                glds16(Wt + (size_t)D_ * D_ + off,     &Bs[1][cid * 8]);
                glds16(Wt + (size_t)2 * D_ * D_ + off, &Bs[2][cid * 8]);
            }
        }
        __syncthreads();

        #pragma unroll
        for (int ks = 0; ks < 2; ++ks) {
            short8 a[2];
            #pragma unroll
            for (int i = 0; i < 2; ++i) {
                const int r = wr * 32 + i * 16 + l16;
                const int ph = (ks * 4 + quad) ^ (r & 7);
                a[i] = *(short8*)&As[r * 64 + ph * 8];
            }
            short8 bq[4];
            #pragma unroll
            for (int j = 0; j < 4; ++j) {
                const int r = wc * 64 + j * 16 + l16;
                const int ph = (ks * 4 + quad) ^ (r & 7);
                bq[j] = *(short8*)&Bs[0][r * 64 + ph * 8];
            }
            #pragma unroll
            for (int i = 0; i < 2; ++i)
                #pragma unroll
                for (int j = 0; j < 4; ++j)
                    accq[i][j] = __builtin_amdgcn_mfma_f32_16x16x32_bf16(
                        a[i], bq[j], accq[i][j], 0, 0, 0);
            if (kv) {
                short8 bk[4], bv[4];
                #pragma unroll
                for (int j = 0; j < 4; ++j) {
                    const int r = wc * 64 + j * 16 + l16;
                    const int ph = (ks * 4 + quad) ^ (r & 7);
                    bk[j] = *(short8*)&Bs[1][r * 64 + ph * 8];
                    bv[j] = *(short8*)&Bs[2][r * 64 + ph * 8];
                }
                #pragma unroll
                for (int i = 0; i < 2; ++i)
                    #pragma unroll
                    for (int j = 0; j < 4; ++j) {
                        acck[i][j] = __builtin_amdgcn_mfma_f32_16x16x32_bf16(
                            a[i], bk[j], acck[i][j], 0, 0, 0);
                        accv[i][j] = __builtin_amdgcn_mfma_f32_16x16x32_bf16(
                            a[i], bv[j], accv[i][j], 0, 0, 0);
                    }
            }
        }
    }

    // epilogue: +bias, scatter into head layouts.
    #pragma unroll
    for (int j = 0; j < 4; ++j) {
        const int col = n0 + wc * 64 + j * 16 + l16;
        const int h = col >> 6, dk = col & (DK_ - 1);
        const float bvq = b0[col], bvk = b1[col], bvv = b2[col];
        #pragma unroll
        for (int i = 0; i < 2; ++i) {
            #pragma unroll
            for (int rr = 0; rr < 4; ++rr) {
                const int row = m0 + wr * 32 + i * 16 + quad * 4 + rr;
                const int s = row & (S_ - 1);
                const size_t hdr = ((size_t)(bidx * H_ + h) * S_ + s) * DK_ + dk;
                qkv[hdr] = f32_to_bf16bits((accq[i][j][rr] + bvq) * QSCALE);
                if (kv) {
                    qkv[(size_t)M_ * D_ + hdr] =
                        f32_to_bf16bits(acck[i][j][rr] + bvk);
                    qkv[(size_t)2 * M_ * D_ +
                        ((size_t)(bidx * H_ + h) * DK_ + dk) * S_ + s] =
                        f32_to_bf16bits(accv[i][j][rr] + bvv);
                }
            }
        }
    }
}

// ---------------------------------------------------------------------------
// attention, 32x32x16 MFMA: block = (b, h, 128 q-rows), 4 waves x 32-q strip.
// 32x32 MFMA does 2x the MACs per 16B/lane operand -> LDS-read bytes per
// FLOP halve (the measured bottleneck).  S^T = K*Q^T per wave (full 64-key
// range, so P stays wave-private, no extra barrier); P packed by truncation
// (bias cancels in P/sum(P)); rowsum fused as P@ones MFMA whose 32x32
// C-layout rows align with the PV accumulator rows (zero shuffles).
// 64 KB LDS = 2 blocks/CU; K/V double-buffered.
// ---------------------------------------------------------------------------
__global__ __launch_bounds__(256, 2) void attention(
    const ushort* __restrict__ qkv, const int* __restrict__ length,
    float* __restrict__ out)
{
    const int b = blockIdx.z, h = blockIdx.y, q0 = blockIdx.x * 128;
    int len = length[b];
    if (len > S_) len = S_;
    if (len < 1) len = 1;
    const int nkt = (len + 63) >> 6;

    const ushort* qb = qkv + ((size_t)(b * H_ + h) * S_ + q0) * DK_;
    const ushort* kb = qkv + (size_t)M_ * D_ + (size_t)(b * H_ + h) * S_ * DK_;
    const ushort* vb = qkv + (size_t)2 * M_ * D_ + (size_t)(b * H_ + h) * DK_ * S_;

    __shared__ __align__(16) ushort Qs[128 * 64];      // 16 KB [q][dk]
    __shared__ __align__(16) ushort Ks[2][64 * 64];    // 16 KB [key][dk]
    __shared__ __align__(16) ushort Vs[2][64 * 64];    // 16 KB [dk][key]
    __shared__ __align__(16) ushort Ps[128 * 64];      // 16 KB [q][key] 8B-swz

    const int t = threadIdx.x, lane = t & 63, wid = t >> 6;
    const int l32 = lane & 31, lhi = lane >> 5;        // 32x32 lane split
    const int qbase = wid * 32;                        // wave's q strip
    const int prow = qbase + l32;                      // this lane's q row
    const int swz = (prow & 7) << 1;                   // even 8B-chunk XOR

    // stage Q (once, 128 rows): 1024 chunks, 4 glds/wave
    #pragma unroll
    for (int j = 0; j < 4; ++j) {
        const int cid = wid * 256 + j * 64 + lane;
        const int row = cid >> 3;
        const int cl  = (cid & 7) ^ (row & 7);
        glds16(qb + (size_t)row * DK_ + cl * 8, &Qs[cid * 8]);
    }
    // K/V tile 0: 512 chunks each, 2 glds/wave each
    #pragma unroll
    for (int j = 0; j < 2; ++j) {
        const int cid = wid * 128 + j * 64 + lane;
        const int row = cid >> 3;
        const int cl  = (cid & 7) ^ (row & 7);
        glds16(kb + (size_t)row * DK_ + cl * 8, &Ks[0][cid * 8]);
        glds16(vb + (size_t)row * S_ + cl * 8,  &Vs[0][cid * 8]);
    }
    __syncthreads();

    // hoist Q fragments: B-operand, n=q=l32 within strip, k=dk (4 ksteps x16)
    short8 qfrag[4];
    #pragma unroll
    for (int ks = 0; ks < 4; ++ks) {
        const int ph = (ks * 2 + lhi) ^ (prow & 7);
        qfrag[ks] = *(short8*)&Qs[prow * 64 + ph * 8];
    }

    short8 ones8;
    #pragma unroll
    for (int i = 0; i < 8; ++i) ones8[i] = (short)0x3F80;

    float16v cacc[2] = {};   // PV acc, ntile = d 0..31 / 32..63
    float16v racc = {};      // rowsum acc

    for (int kt = 0; kt < nkt; ++kt) {
        const int cur = kt & 1, nxt = cur ^ 1;
        if (kt + 1 < nkt) {
            #pragma unroll
            for (int j = 0; j < 2; ++j) {
                const int cid = wid * 128 + j * 64 + lane;
                const int row = cid >> 3;
                const int cl  = (cid & 7) ^ (row & 7);
                glds16(kb + (size_t)((kt + 1) * 64 + row) * DK_ + cl * 8,
                       &Ks[nxt][cid * 8]);
                glds16(vb + (size_t)row * S_ + (kt + 1) * 64 + cl * 8,
                       &Vs[nxt][cid * 8]);
            }
        }

        // S^T: A = K (m=key), B = Q (n=q).  Two 32-key tiles, 4 ksteps each.
        // D[key_local=(reg&3)+8*(reg>>2)+4*lhi][q=l32].
        float16v sacc[2] = {};
        #pragma unroll
        for (int ks = 0; ks < 4; ++ks) {
            const int ph = (ks * 2 + lhi) ^ (l32 & 7);   // key&7 == l32&7
            short8 ak0 = *(short8*)&Ks[cur][ l32       * 64 + ph * 8];
            short8 ak1 = *(short8*)&Ks[cur][(l32 + 32) * 64 + ph * 8];
            sacc[0] = __builtin_amdgcn_mfma_f32_32x32x16_bf16(
                ak0, qfrag[ks], sacc[0], 0, 0, 0);
            sacc[1] = __builtin_amdgcn_mfma_f32_32x32x16_bf16(
                ak1, qfrag[ks], sacc[1], 0, 0, 0);
        }

        // exp2 + (boundary-only) mask + truncation-packed P write.
        // reg = 4g+i -> key = ktile*32 + 4*lhi + 8*g + i  (i=0..3 consecutive)
        const bool full = ((kt + 1) * 64 <= len);
        #pragma unroll
        for (int ktile = 0; ktile < 2; ++ktile) {
            #pragma unroll
            for (int g = 0; g < 4; ++g) {
                float v0 = __builtin_amdgcn_exp2f(sacc[ktile][4 * g + 0]);
                float v1 = __builtin_amdgcn_exp2f(sacc[ktile][4 * g + 1]);
                float v2 = __builtin_amdgcn_exp2f(sacc[ktile][4 * g + 2]);
                float v3 = __builtin_amdgcn_exp2f(sacc[ktile][4 * g + 3]);
                if (!full) {
                    const int kb0 = kt * 64 + ktile * 32 + 4 * lhi + 8 * g;
                    v0 = (kb0 + 0 < len) ? v0 : 0.f;
                    v1 = (kb0 + 1 < len) ? v1 : 0.f;
                    v2 = (kb0 + 2 < len) ? v2 : 0.f;
                    v3 = (kb0 + 3 < len) ? v3 : 0.f;
                }
                uint2 w;
                w.x = (__float_as_uint(v0) >> 16) | (__float_as_uint(v1) & 0xFFFF0000u);
                w.y = (__float_as_uint(v2) >> 16) | (__float_as_uint(v3) & 0xFFFF0000u);
                const int c8 = (ktile * 8 + 2 * g + lhi) ^ swz;
                *(uint2*)&Ps[prow * 64 + c8 * 4] = w;
            }
        }

        // PV + rowsum.  A = P (m=q, k=key, 4 ksteps x16) -- wave-private rows,
        // same-wave LDS RAW (compiler inserts lgkm wait), no barrier.
        short8 ap[4];
        #pragma unroll
        for (int ks = 0; ks < 4; ++ks) {
            const int p = ((ks * 2 + lhi) * 2) ^ swz;
            ap[ks] = *(short8*)&Ps[prow * 64 + p * 4];
        }
        #pragma unroll
        for (int ks = 0; ks < 4; ++ks) {
            #pragma unroll
            for (int nt = 0; nt < 2; ++nt) {
                const int vrow = nt * 32 + l32;          // d row in Vs[dk][key]
                const int ph = (ks * 2 + lhi) ^ (vrow & 7);
                short8 vv = *(short8*)&Vs[cur][vrow * 64 + ph * 8];
                cacc[nt] = __builtin_amdgcn_mfma_f32_32x32x16_bf16(
                    ap[ks], vv, cacc[nt], 0, 0, 0);
            }
            racc = __builtin_amdgcn_mfma_f32_32x32x16_bf16(
                ap[ks], ones8, racc, 0, 0, 0);
        }
        __syncthreads();   // next-stage glds drained; buf[cur] free for kt+2
    }

    // normalize + store fp32.  D rows (m=q) map as (reg&3)+8*(reg>>2)+4*lhi;
    // racc[reg] is the rowsum for exactly cacc[nt][reg]'s q row.
    #pragma unroll
    for (int g = 0; g < 4; ++g) {
        #pragma unroll
        for (int i = 0; i < 4; ++i) {
            const int reg = 4 * g + i;
            const float inv = 1.0f / (racc[reg] + 1e-8f);
            const int q = q0 + qbase + 4 * lhi + 8 * g + i;
            #pragma unroll
            for (int nt = 0; nt < 2; ++nt) {
                const int d = h * 64 + nt * 32 + l32;
                out[((size_t)b * S_ + q) * D_ + d] = cacc[nt][reg] * inv;
            }
        }
    }
}

// ---------------------------------------------------------------------------
extern "C" void kernel_launch(void* const* d_in, const int* in_sizes, int n_in,
                              void* d_out, int out_size, void* d_ws, size_t ws_size,
                              hipStream_t stream)
{
    const float* Q   = (const float*)d_in[0];
    const int*   len = (const int*)d_in[1];
    const float* Wq  = (const float*)d_in[2];
    const float* bq  = (const float*)d_in[3];
    const float* Wk  = (const float*)d_in[4];
    const float* bk  = (const float*)d_in[5];
    const float* Wv  = (const float*)d_in[6];
    const float* bv  = (const float*)d_in[7];
    float* out = (float*)d_out;

    ushort* ws  = (ushort*)d_ws;
    ushort* Xb  = ws;                                   // 4M bf16 = 8 MB
    ushort* Wt  = ws + (size_t)M_ * D_;                 // 3M bf16 = 6 MB
    ushort* qkv = Wt + (size_t)3 * D_ * D_;             // 12M bf16 = 24 MB

    dim3 gPr(16, 16, 11);
    prep<<<gPr, 256, 0, stream>>>(Q, Wq, Wk, Wv, Xb, Wt);

    dim3 gP(M_ / 64, D_ / 128);
    proj_gemm<<<gP, 256, 0, stream>>>(Xb, Wt, bq, bk, bv, len, qkv);

    dim3 gA(S_ / 128, H_, B_);
    attention<<<gA, 256, 0, stream>>>(qkv, len, out);
}

// Round 11
// 161.997 us; speedup vs baseline: 1.0262x; 1.0025x over previous
//
#include <hip/hip_runtime.h>
#include <hip/hip_bf16.h>

#define B_  2
#define S_  2048
#define D_  1024
#define H_  16
#define DK_ 64
#define M_  (B_ * S_)   // 4096

typedef short short8 __attribute__((ext_vector_type(8)));
typedef float float4v __attribute__((ext_vector_type(4)));

// log2(e)/8 : folded into Q at projection so attention exp is a bare v_exp_f32
#define QSCALE 0.18033688011112042f

static __device__ __forceinline__ ushort f32_to_bf16bits(float f) {
    union { __hip_bfloat16 h; ushort u; } cv;
    cv.h = __float2bfloat16(f);
    return cv.u;
}

// async global->LDS, 16B per lane (lands at wave-uniform base + lane*16)
static __device__ __forceinline__ void glds16(const ushort* g, ushort* l) {
    __builtin_amdgcn_global_load_lds(
        (const __attribute__((address_space(1))) unsigned int*)g,
        (__attribute__((address_space(3))) unsigned int*)l, 16, 0, 0);
}

// ---------------------------------------------------------------------------
// prep: z in [0,3) -> transpose+convert W_z[k][n] fp32 -> Wt[n][k] bf16
//       z in [3,11) -> convert X fp32 -> bf16
// ---------------------------------------------------------------------------
__global__ __launch_bounds__(256) void prep(
    const float* __restrict__ X, const float* __restrict__ W0,
    const float* __restrict__ W1, const float* __restrict__ W2,
    ushort* __restrict__ Xb, ushort* __restrict__ Wt)
{
    const int z = blockIdx.z;
    const int t = threadIdx.x;

    if (z >= 3) {   // convert X
        const int blk = (z - 3) * 256 + blockIdx.y * 16 + blockIdx.x;
        const int i = blk * 2048 + t * 8;
        float4v a = *(const float4v*)(X + i);
        float4v b = *(const float4v*)(X + i + 4);
        short8 o;
        o[0] = (short)f32_to_bf16bits(a[0]); o[1] = (short)f32_to_bf16bits(a[1]);
        o[2] = (short)f32_to_bf16bits(a[2]); o[3] = (short)f32_to_bf16bits(a[3]);
        o[4] = (short)f32_to_bf16bits(b[0]); o[5] = (short)f32_to_bf16bits(b[1]);
        o[6] = (short)f32_to_bf16bits(b[2]); o[7] = (short)f32_to_bf16bits(b[3]);
        *(short8*)(Xb + i) = o;
        return;
    }

    const float* W = (z == 0) ? W0 : ((z == 1) ? W1 : W2);
    ushort* out = Wt + (size_t)z * D_ * D_;

    __shared__ ushort tile[64 * 72];
    int n0 = blockIdx.x * 64, k0 = blockIdx.y * 64;
    int r = t >> 3, g = t & 7;

    #pragma unroll
    for (int p = 0; p < 2; ++p) {
        int rr = r + p * 32;
        const float* src = W + (size_t)(k0 + rr) * D_ + n0 + g * 8;
        float4v a = *(const float4v*)src;
        float4v b = *(const float4v*)(src + 4);
        short8 o;
        o[0] = (short)f32_to_bf16bits(a[0]); o[1] = (short)f32_to_bf16bits(a[1]);
        o[2] = (short)f32_to_bf16bits(a[2]); o[3] = (short)f32_to_bf16bits(a[3]);
        o[4] = (short)f32_to_bf16bits(b[0]); o[5] = (short)f32_to_bf16bits(b[1]);
        o[6] = (short)f32_to_bf16bits(b[2]); o[7] = (short)f32_to_bf16bits(b[3]);
        *(short8*)&tile[rr * 72 + g * 8] = o;
    }
    __syncthreads();
    #pragma unroll
    for (int p = 0; p < 2; ++p) {
        int rr = r + p * 32;
        short8 v;
        #pragma unroll
        for (int i = 0; i < 8; ++i)
            v[i] = (short)tile[(g * 8 + i) * 72 + rr];
        *(short8*)(out + (size_t)(n0 + rr) * D_ + k0 + g * 8) = v;
    }
}

// ---------------------------------------------------------------------------
// FUSED-z QKV projection (round-7/8 best-known): one block = (m 64, n 128)
// computing q, k AND v.  A staged once, 48 MFMA per barrier pair; 56 KB LDS
// = 2 blocks/CU.  k/v skipped (block-uniform) beyond length[b].
// z==0 (Q) epilogue folds score-scale*log2(e) into the values.
// ---------------------------------------------------------------------------
__global__ __launch_bounds__(256, 2) void proj_gemm(
    const ushort* __restrict__ X,    // [4096][1024] bf16
    const ushort* __restrict__ Wt,   // [3][1024][1024] bf16, n-major
    const float* __restrict__ b0, const float* __restrict__ b1,
    const float* __restrict__ b2,
    const int* __restrict__ length,
    ushort* __restrict__ qkv)        // [3][4M] bf16
{
    const int m0 = blockIdx.x * 64, n0 = blockIdx.y * 128;
    const int bidx = m0 >> 11;
    const int s0 = m0 & (S_ - 1);
    const bool kv = (s0 < length[bidx]);   // block-uniform

    __shared__ __align__(16) ushort As[64 * 64];        //  8 KB
    __shared__ __align__(16) ushort Bs[3][128 * 64];    // 48 KB

    const int t = threadIdx.x;
    const int lane = t & 63, wid = t >> 6;
    const int quad = lane >> 4, l16 = lane & 15;
    const int wr = wid >> 1, wc = wid & 1;

    float4v accq[2][4] = {}, acck[2][4] = {}, accv[2][4] = {};

    for (int kt = 0; kt < 16; ++kt) {
        const int k0 = kt * 64;
        __syncthreads();
        #pragma unroll
        for (int j = 0; j < 2; ++j) {          // A: 512 chunks, 128/wave
            const int cid = wid * 128 + j * 64 + lane;
            const int row = cid >> 3;
            const int cl  = (cid & 7) ^ (row & 7);
            glds16(X + (size_t)(m0 + row) * D_ + k0 + cl * 8, &As[cid * 8]);
        }
        #pragma unroll
        for (int j = 0; j < 4; ++j) {          // B panels: 1024 chunks each
            const int cid = wid * 256 + j * 64 + lane;
            const int row = cid >> 3;
            const int cl  = (cid & 7) ^ (row & 7);
            const size_t off = (size_t)(n0 + row) * D_ + k0 + cl * 8;
            glds16(Wt + off, &Bs[0][cid * 8]);
            if (kv) {
                glds16(Wt + (size_t)D_ * D_ + off,     &Bs[1][cid * 8]);
                glds16(Wt + (size_t)2 * D_ * D_ + off, &Bs[2][cid * 8]);
            }
        }
        __syncthreads();

        #pragma unroll
        for (int ks = 0; ks < 2; ++ks) {
            short8 a[2];
            #pragma unroll
            for (int i = 0; i < 2; ++i) {
                const int r = wr * 32 + i * 16 + l16;
                const int ph = (ks * 4 + quad) ^ (r & 7);
                a[i] = *(short8*)&As[r * 64 + ph * 8];
            }
            short8 bq[4];
            #pragma unroll
            for (int j = 0; j < 4; ++j) {
                const int r = wc * 64 + j * 16 + l16;
                const int ph = (ks * 4 + quad) ^ (r & 7);
                bq[j] = *(short8*)&Bs[0][r * 64 + ph * 8];
            }
            #pragma unroll
            for (int i = 0; i < 2; ++i)
                #pragma unroll
                for (int j = 0; j < 4; ++j)
                    accq[i][j] = __builtin_amdgcn_mfma_f32_16x16x32_bf16(
                        a[i], bq[j], accq[i][j], 0, 0, 0);
            if (kv) {
                short8 bk[4], bv[4];
                #pragma unroll
                for (int j = 0; j < 4; ++j) {
                    const int r = wc * 64 + j * 16 + l16;
                    const int ph = (ks * 4 + quad) ^ (r & 7);
                    bk[j] = *(short8*)&Bs[1][r * 64 + ph * 8];
                    bv[j] = *(short8*)&Bs[2][r * 64 + ph * 8];
                }
                #pragma unroll
                for (int i = 0; i < 2; ++i)
                    #pragma unroll
                    for (int j = 0; j < 4; ++j) {
                        acck[i][j] = __builtin_amdgcn_mfma_f32_16x16x32_bf16(
                            a[i], bk[j], acck[i][j], 0, 0, 0);
                        accv[i][j] = __builtin_amdgcn_mfma_f32_16x16x32_bf16(
                            a[i], bv[j], accv[i][j], 0, 0, 0);
                    }
            }
        }
    }

    // epilogue: +bias, scatter into head layouts.
    #pragma unroll
    for (int j = 0; j < 4; ++j) {
        const int col = n0 + wc * 64 + j * 16 + l16;
        const int h = col >> 6, dk = col & (DK_ - 1);
        const float bvq = b0[col], bvk = b1[col], bvv = b2[col];
        #pragma unroll
        for (int i = 0; i < 2; ++i) {
            #pragma unroll
            for (int rr = 0; rr < 4; ++rr) {
                const int row = m0 + wr * 32 + i * 16 + quad * 4 + rr;
                const int s = row & (S_ - 1);
                const size_t hdr = ((size_t)(bidx * H_ + h) * S_ + s) * DK_ + dk;
                qkv[hdr] = f32_to_bf16bits((accq[i][j][rr] + bvq) * QSCALE);
                if (kv) {
                    qkv[(size_t)M_ * D_ + hdr] =
                        f32_to_bf16bits(acck[i][j][rr] + bvk);
                    qkv[(size_t)2 * M_ * D_ +
                        ((size_t)(bidx * H_ + h) * DK_ + dk) * S_ + s] =
                        f32_to_bf16bits(accv[i][j][rr] + bvv);
                }
            }
        }
    }
}

// ---------------------------------------------------------------------------
// attention: block = (b, h, 128 q-rows), 4 waves x TWO 16-q strips.
// The 8 K-fragments and 8 V-fragments per k-tile are read ONCE per wave into
// registers and reused for both strips -> LDS b128 reads per wave-ktile drop
// 36 -> 20 for 2x the q rows (the measured bottleneck is LDS read
// throughput).  16x16 MFMA keeps the conflict-free swizzle.  Qs unioned with
// Ps after the qfrag hoist (wave-private rows [32w,32w+32), barrier-free).
// Grid is q-fastest for K/V L2 locality (r9 lesson).  ones-MFMA rowsum,
// truncation pack, dbuf K/V as in round 8.
// ---------------------------------------------------------------------------
__global__ __launch_bounds__(256, 3) void attention(
    const ushort* __restrict__ qkv, const int* __restrict__ length,
    float* __restrict__ out)
{
    const int b = blockIdx.z, h = blockIdx.y, q0 = blockIdx.x * 128;
    int len = length[b];
    if (len > S_) len = S_;
    if (len < 1) len = 1;
    const int nkt = (len + 63) >> 6;

    const ushort* qb = qkv + ((size_t)(b * H_ + h) * S_ + q0) * DK_;
    const ushort* kb = qkv + (size_t)M_ * D_ + (size_t)(b * H_ + h) * S_ * DK_;
    const ushort* vb = qkv + (size_t)2 * M_ * D_ + (size_t)(b * H_ + h) * DK_ * S_;

    __shared__ __align__(16) ushort QPs[128 * 64];     // 16 KB Q then P (union)
    __shared__ __align__(16) ushort Ks[2][64 * 64];    // 16 KB [key][dk]
    __shared__ __align__(16) ushort Vs[2][64 * 64];    // 16 KB [dk][key]

    const int t = threadIdx.x, lane = t & 63, wid = t >> 6;
    const int quad = lane >> 4, l16 = lane & 15;
    const int e8 = (l16 & 7) << 1;   // even XOR phase for P rows (row&7==l16&7)

    // stage Q (once, wave w stages its own rows 32w..32w+31) + K/V tile 0
    #pragma unroll
    for (int j = 0; j < 4; ++j) {
        const int cid = wid * 256 + j * 64 + lane;
        const int row = cid >> 3;
        const int cl  = (cid & 7) ^ (row & 7);
        glds16(qb + (size_t)row * DK_ + cl * 8, &QPs[cid * 8]);
    }
    #pragma unroll
    for (int j = 0; j < 2; ++j) {
        const int cid = wid * 128 + j * 64 + lane;
        const int row = cid >> 3;
        const int cl  = (cid & 7) ^ (row & 7);
        glds16(kb + (size_t)row * DK_ + cl * 8, &Ks[0][cid * 8]);
        glds16(vb + (size_t)row * S_ + cl * 8,  &Vs[0][cid * 8]);
    }
    __syncthreads();

    // hoist Q fragments for both strips; QPs rows then free for P
    short8 qfrag[2][2];
    #pragma unroll
    for (int st = 0; st < 2; ++st)
        #pragma unroll
        for (int ks = 0; ks < 2; ++ks) {
            const int qrow = wid * 32 + st * 16 + l16;
            const int ph = (ks * 4 + quad) ^ (qrow & 7);
            qfrag[st][ks] = *(short8*)&QPs[qrow * 64 + ph * 8];
        }

    short8 ones8;
    #pragma unroll
    for (int i = 0; i < 8; ++i) ones8[i] = (short)0x3F80;

    float4v cacc[2][4] = {};
    float4v racc[2] = {};

    for (int kt = 0; kt < nkt; ++kt) {
        const int cur = kt & 1, nxt = cur ^ 1;
        if (kt + 1 < nkt) {
            #pragma unroll
            for (int j = 0; j < 2; ++j) {
                const int cid = wid * 128 + j * 64 + lane;
                const int row = cid >> 3;
                const int cl  = (cid & 7) ^ (row & 7);
                glds16(kb + (size_t)((kt + 1) * 64 + row) * DK_ + cl * 8,
                       &Ks[nxt][cid * 8]);
                glds16(vb + (size_t)row * S_ + (kt + 1) * 64 + cl * 8,
                       &Vs[nxt][cid * 8]);
            }
        }

        // S^T = K * Q^T: read each K-fragment ONCE, use for both strips.
        float4v sacc[2][4] = {};
        #pragma unroll
        for (int ks = 0; ks < 2; ++ks)
            #pragma unroll
            for (int ct = 0; ct < 4; ++ct) {
                const int krow = ct * 16 + l16;
                const int pha = (ks * 4 + quad) ^ (krow & 7);
                short8 ak = *(short8*)&Ks[cur][krow * 64 + pha * 8];
                #pragma unroll
                for (int st = 0; st < 2; ++st)
                    sacc[st][ct] = __builtin_amdgcn_mfma_f32_16x16x32_bf16(
                        ak, qfrag[st][ks], sacc[st][ct], 0, 0, 0);
            }

        // exp2 + (boundary-only) mask + truncation-packed P write (per strip)
        const bool full = ((kt + 1) * 64 <= len);
        #pragma unroll
        for (int st = 0; st < 2; ++st) {
            const int qrow = wid * 32 + st * 16 + l16;
            #pragma unroll
            for (int ct = 0; ct < 4; ++ct) {
                float v0 = __builtin_amdgcn_exp2f(sacc[st][ct][0]);
                float v1 = __builtin_amdgcn_exp2f(sacc[st][ct][1]);
                float v2 = __builtin_amdgcn_exp2f(sacc[st][ct][2]);
                float v3 = __builtin_amdgcn_exp2f(sacc[st][ct][3]);
                if (!full) {
                    const int kb0 = kt * 64 + ct * 16 + quad * 4;
                    v0 = (kb0 + 0 < len) ? v0 : 0.f;
                    v1 = (kb0 + 1 < len) ? v1 : 0.f;
                    v2 = (kb0 + 2 < len) ? v2 : 0.f;
                    v3 = (kb0 + 3 < len) ? v3 : 0.f;
                }
                uint2 w;
                w.x = (__float_as_uint(v0) >> 16) | (__float_as_uint(v1) & 0xFFFF0000u);
                w.y = (__float_as_uint(v2) >> 16) | (__float_as_uint(v3) & 0xFFFF0000u);
                const int c8 = (ct * 4 + quad) ^ e8;        // 8B-chunk swizzle
                *(uint2*)&QPs[qrow * 64 + c8 * 4] = w;
            }
        }

        // P @ V + rowsum: read each V-fragment ONCE, use for both strips.
        // P strips are wave-private rows: same-wave LDS RAW, no barrier.
        short8 ap[2][2];
        #pragma unroll
        for (int st = 0; st < 2; ++st)
            #pragma unroll
            for (int ks = 0; ks < 2; ++ks) {
                const int qrow = wid * 32 + st * 16 + l16;
                const int pp = ((ks * 4 + quad) * 2) ^ e8;   // even 8B chunk
                ap[st][ks] = *(short8*)&QPs[qrow * 64 + pp * 4];
            }
        #pragma unroll
        for (int ks = 0; ks < 2; ++ks) {
            #pragma unroll
            for (int ct = 0; ct < 4; ++ct) {
                const int vrow = ct * 16 + l16;
                const int phv = (ks * 4 + quad) ^ (vrow & 7);
                short8 vv = *(short8*)&Vs[cur][vrow * 64 + phv * 8];
                #pragma unroll
                for (int st = 0; st < 2; ++st)
                    cacc[st][ct] = __builtin_amdgcn_mfma_f32_16x16x32_bf16(
                        ap[st][ks], vv, cacc[st][ct], 0, 0, 0);
            }
            #pragma unroll
            for (int st = 0; st < 2; ++st)
                racc[st] = __builtin_amdgcn_mfma_f32_16x16x32_bf16(
                    ap[st][ks], ones8, racc[st], 0, 0, 0);
        }
        __syncthreads();   // next-stage glds drained; buf[cur] free for kt+2
    }

    // normalize + store fp32.  racc[st][rr] = rowsum for q = quad*4+rr of
    // strip st, in exactly the lane that holds cacc[st][ct][rr].
    #pragma unroll
    for (int st = 0; st < 2; ++st)
        #pragma unroll
        for (int rr = 0; rr < 4; ++rr) {
            const float inv = 1.0f / (racc[st][rr] + 1e-8f);
            const int q = q0 + wid * 32 + st * 16 + quad * 4 + rr;
            #pragma unroll
            for (int ct = 0; ct < 4; ++ct) {
                const int d = h * 64 + ct * 16 + l16;
                out[((size_t)b * S_ + q) * D_ + d] = cacc[st][ct][rr] * inv;
            }
        }
}

// ---------------------------------------------------------------------------
extern "C" void kernel_launch(void* const* d_in, const int* in_sizes, int n_in,
                              void* d_out, int out_size, void* d_ws, size_t ws_size,
                              hipStream_t stream)
{
    const float* Q   = (const float*)d_in[0];
    const int*   len = (const int*)d_in[1];
    const float* Wq  = (const float*)d_in[2];
    const float* bq  = (const float*)d_in[3];
    const float* Wk  = (const float*)d_in[4];
    const float* bk  = (const float*)d_in[5];
    const float* Wv  = (const float*)d_in[6];
    const float* bv  = (const float*)d_in[7];
    float* out = (float*)d_out;

    ushort* ws  = (ushort*)d_ws;
    ushort* Xb  = ws;                                   // 4M bf16 = 8 MB
    ushort* Wt  = ws + (size_t)M_ * D_;                 // 3M bf16 = 6 MB
    ushort* qkv = Wt + (size_t)3 * D_ * D_;             // 12M bf16 = 24 MB

    dim3 gPr(16, 16, 11);
    prep<<<gPr, 256, 0, stream>>>(Q, Wq, Wk, Wv, Xb, Wt);

    dim3 gP(M_ / 64, D_ / 128);
    proj_gemm<<<gP, 256, 0, stream>>>(Xb, Wt, bq, bk, bv, len, qkv);

    dim3 gA(S_ / 128, H_, B_);
    attention<<<gA, 256, 0, stream>>>(qkv, len, out);
}